// Round 2
// baseline (165.132 us; speedup 1.0000x reference)
//
#include <hip/hip_runtime.h>
#include <hip/hip_bf16.h>

#define IMG_W 1024
#define IMG_H 1024
#define TH    32          // output rows per block
#define VX    4           // pixels per thread (float4)
#define NTHREADS 256      // 256*4 = 1024 = full row width

#define ALPHA_ 0.85f
#define BETA_  0.15f
#define C1_    (0.01f * 0.01f)
#define C2_    (0.03f * 0.03f)

struct HRow { float p[VX], t[VX], pp[VX], tt[VX], pt[VX]; };

__device__ __forceinline__ void hzero(HRow& h) {
#pragma unroll
    for (int j = 0; j < VX; ++j) {
        h.p[j] = 0.f; h.t[j] = 0.f; h.pp[j] = 0.f; h.tt[j] = 0.f; h.pt[j] = 0.f;
    }
}

__device__ __forceinline__ void load_row(const float* __restrict__ Pr,
                                         const float* __restrict__ Tr,
                                         int x, float pv[6], float tv[6]) {
    const float4 p4 = *reinterpret_cast<const float4*>(Pr + x);
    const float4 t4 = *reinterpret_cast<const float4*>(Tr + x);
    pv[1] = p4.x; pv[2] = p4.y; pv[3] = p4.z; pv[4] = p4.w;
    tv[1] = t4.x; tv[2] = t4.y; tv[3] = t4.z; tv[4] = t4.w;
    pv[0] = (x > 0)          ? Pr[x - 1]  : 0.f;   // zero-pad at image left edge
    pv[5] = (x + VX < IMG_W) ? Pr[x + VX] : 0.f;   // zero-pad at image right edge
    tv[0] = (x > 0)          ? Tr[x - 1]  : 0.f;
    tv[5] = (x + VX < IMG_W) ? Tr[x + VX] : 0.f;
}

__device__ __forceinline__ void hsum(const float pv[6], const float tv[6], HRow& h) {
#pragma unroll
    for (int j = 0; j < VX; ++j) {
        const float a = pv[j], b = pv[j + 1], c = pv[j + 2];
        const float u = tv[j], v = tv[j + 1], w = tv[j + 2];
        h.p[j]  = a + b + c;
        h.t[j]  = u + v + w;
        h.pp[j] = a * a + b * b + c * c;
        h.tt[j] = u * u + v * v + w * w;
        h.pt[j] = a * u + b * v + c * w;
    }
}

__global__ void __launch_bounds__(NTHREADS)
ssim_l1_kernel(const float* __restrict__ pred, const float* __restrict__ tgt,
               float* __restrict__ ws) {
    const int tid = threadIdx.x;
    const int x   = tid * VX;
    const int y0  = blockIdx.y * TH;
    const size_t base = (size_t)blockIdx.z * (size_t)(IMG_W * IMG_H);
    const float* __restrict__ P = pred + base;
    const float* __restrict__ T = tgt + base;

    float ssim_acc = 0.f, l1_acc = 0.f;
    HRow A, B, C;
    float pv[6], tv[6];

    // --- prologue: row y0-1 (may be above the image -> zeros) and row y0 ---
    if (y0 - 1 >= 0) {
        load_row(P + (size_t)(y0 - 1) * IMG_W, T + (size_t)(y0 - 1) * IMG_W, x, pv, tv);
        hsum(pv, tv, A);
    } else {
        hzero(A);
    }
    {
        load_row(P + (size_t)y0 * IMG_W, T + (size_t)y0 * IMG_W, x, pv, tv);
        hsum(pv, tv, B);
#pragma unroll
        for (int k = 1; k <= VX; ++k) l1_acc += fabsf(pv[k] - tv[k]);
    }

    // --- main loop: emit output rows y0 .. y0+TH-1 ---
    const float inv9 = 1.0f / 9.0f;
    for (int yo = y0; yo < y0 + TH; ++yo) {
        const int r = yo + 1;   // new bottom row of the vertical window
        if (r < IMG_H) {
            load_row(P + (size_t)r * IMG_W, T + (size_t)r * IMG_W, x, pv, tv);
            hsum(pv, tv, C);
            if (r < y0 + TH) {  // r is a central (owned) row of this block
#pragma unroll
                for (int k = 1; k <= VX; ++k) l1_acc += fabsf(pv[k] - tv[k]);
            }
        } else {
            hzero(C);
        }

#pragma unroll
        for (int j = 0; j < VX; ++j) {
            const float Sp  = A.p[j]  + B.p[j]  + C.p[j];
            const float St  = A.t[j]  + B.t[j]  + C.t[j];
            const float Spp = A.pp[j] + B.pp[j] + C.pp[j];
            const float Stt = A.tt[j] + B.tt[j] + C.tt[j];
            const float Spt = A.pt[j] + B.pt[j] + C.pt[j];

            const float mux  = Sp * inv9;
            const float muy  = St * inv9;
            const float mux2 = mux * mux;
            const float muy2 = muy * muy;
            const float muxy = mux * muy;
            const float sx   = Spp * inv9 - mux2;
            const float sy   = Stt * inv9 - muy2;
            const float sxy  = Spt * inv9 - muxy;

            const float n = (2.0f * muxy + C1_) * (2.0f * sxy + C2_);
            const float d = (mux2 + muy2 + C1_) * (sx + sy + C2_);
            const float ssim = n * __builtin_amdgcn_rcpf(d);  // d >= C1_*C2_ > 0
            float v = 0.5f - 0.5f * ssim;
            v = fminf(fmaxf(v, 0.0f), 1.0f);
            ssim_acc += v;
        }
        A = B;
        B = C;
    }

    // --- reduction: wave shuffle -> LDS across 4 waves -> atomicAdd ---
    float s = ssim_acc, l = l1_acc;
#pragma unroll
    for (int off = 32; off > 0; off >>= 1) {
        s += __shfl_down(s, off, 64);
        l += __shfl_down(l, off, 64);
    }
    __shared__ float red_s[NTHREADS / 64];
    __shared__ float red_l[NTHREADS / 64];
    const int wid = tid >> 6, lane = tid & 63;
    if (lane == 0) { red_s[wid] = s; red_l[wid] = l; }
    __syncthreads();
    if (tid == 0) {
        float ss = 0.f, ll = 0.f;
#pragma unroll
        for (int w = 0; w < NTHREADS / 64; ++w) { ss += red_s[w]; ll += red_l[w]; }
        atomicAdd(&ws[0], ss);
        atomicAdd(&ws[1], ll);
    }
}

__global__ void zero_ws_kernel(float* __restrict__ ws) {
    ws[0] = 0.f;
    ws[1] = 0.f;
}

__global__ void finalize_kernel(const float* __restrict__ ws,
                                float* __restrict__ out, float inv_total) {
    const float ssim = ws[0] * inv_total;
    const float l1   = ws[1] * inv_total;
    out[0] = ALPHA_ * ssim + BETA_ * l1;   // d_out is float32 (reference output dtype)
}

extern "C" void kernel_launch(void* const* d_in, const int* in_sizes, int n_in,
                              void* d_out, int out_size, void* d_ws, size_t ws_size,
                              hipStream_t stream) {
    const float* pred = (const float*)d_in[0];
    const float* tgt  = (const float*)d_in[1];
    float* ws = (float*)d_ws;

    const int total = in_sizes[0];                 // N * H * W = 16 * 1024 * 1024
    const int nimg  = total / (IMG_W * IMG_H);     // 16

    zero_ws_kernel<<<1, 1, 0, stream>>>(ws);

    dim3 grid(1, IMG_H / TH, nimg);                // (1, 32, 16) = 512 blocks
    ssim_l1_kernel<<<grid, NTHREADS, 0, stream>>>(pred, tgt, ws);

    finalize_kernel<<<1, 1, 0, stream>>>(ws, (float*)d_out,
                                         1.0f / (float)total);
}

// Round 3
// 164.567 us; speedup vs baseline: 1.0034x; 1.0034x over previous
//
#include <hip/hip_runtime.h>
#include <hip/hip_bf16.h>

#define IMG_W 1024
#define IMG_H 1024
#define TH    8           // output rows per block: 2048 blocks -> 8 blocks/CU -> 32 waves/CU
#define VX    4           // pixels per thread (float4)
#define NTHREADS 256      // 256*4 = 1024 = full row width

#define ALPHA_ 0.85f
#define BETA_  0.15f
#define C1_    (0.01f * 0.01f)
#define C2_    (0.03f * 0.03f)

struct HRow { float p[VX], t[VX], pp[VX], tt[VX], pt[VX]; };

__device__ __forceinline__ void hzero(HRow& h) {
#pragma unroll
    for (int j = 0; j < VX; ++j) {
        h.p[j] = 0.f; h.t[j] = 0.f; h.pp[j] = 0.f; h.tt[j] = 0.f; h.pt[j] = 0.f;
    }
}

__device__ __forceinline__ void load_row(const float* __restrict__ Pr,
                                         const float* __restrict__ Tr,
                                         int x, float pv[6], float tv[6]) {
    const float4 p4 = *reinterpret_cast<const float4*>(Pr + x);
    const float4 t4 = *reinterpret_cast<const float4*>(Tr + x);
    pv[1] = p4.x; pv[2] = p4.y; pv[3] = p4.z; pv[4] = p4.w;
    tv[1] = t4.x; tv[2] = t4.y; tv[3] = t4.z; tv[4] = t4.w;
    pv[0] = (x > 0)          ? Pr[x - 1]  : 0.f;   // zero-pad at image left edge
    pv[5] = (x + VX < IMG_W) ? Pr[x + VX] : 0.f;   // zero-pad at image right edge
    tv[0] = (x > 0)          ? Tr[x - 1]  : 0.f;
    tv[5] = (x + VX < IMG_W) ? Tr[x + VX] : 0.f;
}

__device__ __forceinline__ void hsum(const float pv[6], const float tv[6], HRow& h) {
#pragma unroll
    for (int j = 0; j < VX; ++j) {
        const float a = pv[j], b = pv[j + 1], c = pv[j + 2];
        const float u = tv[j], v = tv[j + 1], w = tv[j + 2];
        h.p[j]  = a + b + c;
        h.t[j]  = u + v + w;
        h.pp[j] = a * a + b * b + c * c;
        h.tt[j] = u * u + v * v + w * w;
        h.pt[j] = a * u + b * v + c * w;
    }
}

// Each block reduces to one (ssim, l1) pair. mode=0: write partials to
// ws[2*bid]; mode=1: atomicAdd into ws[0..1] (small-ws fallback).
template <int MODE>
__global__ void __launch_bounds__(NTHREADS)
ssim_l1_kernel(const float* __restrict__ pred, const float* __restrict__ tgt,
               float* __restrict__ ws) {
    const int tid = threadIdx.x;
    const int x   = tid * VX;
    const int y0  = blockIdx.y * TH;
    const size_t base = (size_t)blockIdx.z * (size_t)(IMG_W * IMG_H);
    const float* __restrict__ P = pred + base;
    const float* __restrict__ T = tgt + base;

    float ssim_acc = 0.f, l1_acc = 0.f;
    HRow A, B, C;
    float pv[6], tv[6];

    // --- prologue: row y0-1 (may be above the image -> zeros) and row y0 ---
    if (y0 - 1 >= 0) {
        load_row(P + (size_t)(y0 - 1) * IMG_W, T + (size_t)(y0 - 1) * IMG_W, x, pv, tv);
        hsum(pv, tv, A);
    } else {
        hzero(A);
    }
    {
        load_row(P + (size_t)y0 * IMG_W, T + (size_t)y0 * IMG_W, x, pv, tv);
        hsum(pv, tv, B);
#pragma unroll
        for (int k = 1; k <= VX; ++k) l1_acc += fabsf(pv[k] - tv[k]);
    }

    // --- main loop: emit output rows y0 .. y0+TH-1 ---
    const float inv9 = 1.0f / 9.0f;
#pragma unroll
    for (int i = 0; i < TH; ++i) {
        const int yo = y0 + i;
        const int r  = yo + 1;  // new bottom row of the vertical window
        if (r < IMG_H) {
            load_row(P + (size_t)r * IMG_W, T + (size_t)r * IMG_W, x, pv, tv);
            hsum(pv, tv, C);
            if (i < TH - 1) {   // r is a central (owned) row of this block
#pragma unroll
                for (int k = 1; k <= VX; ++k) l1_acc += fabsf(pv[k] - tv[k]);
            }
        } else {
            hzero(C);
        }

#pragma unroll
        for (int j = 0; j < VX; ++j) {
            const float Sp  = A.p[j]  + B.p[j]  + C.p[j];
            const float St  = A.t[j]  + B.t[j]  + C.t[j];
            const float Spp = A.pp[j] + B.pp[j] + C.pp[j];
            const float Stt = A.tt[j] + B.tt[j] + C.tt[j];
            const float Spt = A.pt[j] + B.pt[j] + C.pt[j];

            const float mux  = Sp * inv9;
            const float muy  = St * inv9;
            const float mux2 = mux * mux;
            const float muy2 = muy * muy;
            const float muxy = mux * muy;
            const float sx   = Spp * inv9 - mux2;
            const float sy   = Stt * inv9 - muy2;
            const float sxy  = Spt * inv9 - muxy;

            const float n = (2.0f * muxy + C1_) * (2.0f * sxy + C2_);
            const float d = (mux2 + muy2 + C1_) * (sx + sy + C2_);
            const float ssim = n * __builtin_amdgcn_rcpf(d);  // d >= C1_*C2_ > 0
            float v = 0.5f - 0.5f * ssim;
            v = fminf(fmaxf(v, 0.0f), 1.0f);
            ssim_acc += v;
        }
        A = B;
        B = C;
    }

    // --- reduction: wave shuffle -> LDS across 4 waves -> one write/block ---
    float s = ssim_acc, l = l1_acc;
#pragma unroll
    for (int off = 32; off > 0; off >>= 1) {
        s += __shfl_down(s, off, 64);
        l += __shfl_down(l, off, 64);
    }
    __shared__ float red_s[NTHREADS / 64];
    __shared__ float red_l[NTHREADS / 64];
    const int wid = tid >> 6, lane = tid & 63;
    if (lane == 0) { red_s[wid] = s; red_l[wid] = l; }
    __syncthreads();
    if (tid == 0) {
        float ss = 0.f, ll = 0.f;
#pragma unroll
        for (int w = 0; w < NTHREADS / 64; ++w) { ss += red_s[w]; ll += red_l[w]; }
        if (MODE == 0) {
            const int bid = blockIdx.z * gridDim.y + blockIdx.y;
            ws[2 * bid]     = ss;   // every slot written every call: no pre-zero needed
            ws[2 * bid + 1] = ll;
        } else {
            atomicAdd(&ws[0], ss);
            atomicAdd(&ws[1], ll);
        }
    }
}

__global__ void zero_ws_kernel(float* __restrict__ ws) {
    ws[0] = 0.f;
    ws[1] = 0.f;
}

// Sum nblocks (ssim,l1) pairs from ws and emit the final scalar.
__global__ void __launch_bounds__(256)
finalize_partials_kernel(const float* __restrict__ ws, float* __restrict__ out,
                         int nblocks, float inv_total) {
    const int tid = threadIdx.x;
    float s = 0.f, l = 0.f;
    for (int i = tid; i < nblocks; i += 256) {
        s += ws[2 * i];
        l += ws[2 * i + 1];
    }
#pragma unroll
    for (int off = 32; off > 0; off >>= 1) {
        s += __shfl_down(s, off, 64);
        l += __shfl_down(l, off, 64);
    }
    __shared__ float red_s[4], red_l[4];
    const int wid = tid >> 6, lane = tid & 63;
    if (lane == 0) { red_s[wid] = s; red_l[wid] = l; }
    __syncthreads();
    if (tid == 0) {
        float ss = red_s[0] + red_s[1] + red_s[2] + red_s[3];
        float ll = red_l[0] + red_l[1] + red_l[2] + red_l[3];
        out[0] = ALPHA_ * (ss * inv_total) + BETA_ * (ll * inv_total);
    }
}

__global__ void finalize_atomic_kernel(const float* __restrict__ ws,
                                       float* __restrict__ out, float inv_total) {
    out[0] = ALPHA_ * (ws[0] * inv_total) + BETA_ * (ws[1] * inv_total);
}

extern "C" void kernel_launch(void* const* d_in, const int* in_sizes, int n_in,
                              void* d_out, int out_size, void* d_ws, size_t ws_size,
                              hipStream_t stream) {
    const float* pred = (const float*)d_in[0];
    const float* tgt  = (const float*)d_in[1];
    float* ws = (float*)d_ws;

    const int total = in_sizes[0];                 // N * H * W = 16 * 1024 * 1024
    const int nimg  = total / (IMG_W * IMG_H);     // 16
    const int nblk  = nimg * (IMG_H / TH);         // 16 * 128 = 2048
    const float inv_total = 1.0f / (float)total;

    dim3 grid(1, IMG_H / TH, nimg);

    if (ws_size >= (size_t)(2 * nblk) * sizeof(float)) {
        // partials path: no pre-zero, no atomics
        ssim_l1_kernel<0><<<grid, NTHREADS, 0, stream>>>(pred, tgt, ws);
        finalize_partials_kernel<<<1, 256, 0, stream>>>(ws, (float*)d_out,
                                                        nblk, inv_total);
    } else {
        // fallback: atomic accumulation into ws[0..1]
        zero_ws_kernel<<<1, 1, 0, stream>>>(ws);
        ssim_l1_kernel<1><<<grid, NTHREADS, 0, stream>>>(pred, tgt, ws);
        finalize_atomic_kernel<<<1, 1, 0, stream>>>(ws, (float*)d_out, inv_total);
    }
}